// Round 5
// baseline (490.522 us; speedup 1.0000x reference)
//
#include <hip/hip_runtime.h>
#include <hip/hip_cooperative_groups.h>
#include <math.h>

namespace cg = cooperative_groups;

typedef __attribute__((ext_vector_type(8))) short bf16x8;
typedef __attribute__((ext_vector_type(4))) float f32x4;

static __device__ __forceinline__ float fast_elu(float x) {
    return x > 0.0f ? x : __expf(x) - 1.0f;
}

static __device__ __forceinline__ unsigned short f2bf(float f) {
    unsigned int u = __float_as_uint(f);
    unsigned int r = (u + 0x7FFFu + ((u >> 16) & 1u)) >> 16;
    return (unsigned short)r;
}

static __device__ __forceinline__ bf16x8 cvt8(const float* __restrict__ s) {
    float4 a = *reinterpret_cast<const float4*>(s);
    float4 b = *reinterpret_cast<const float4*>(s + 4);
    bf16x8 r;
    r[0] = (short)f2bf(a.x); r[1] = (short)f2bf(a.y);
    r[2] = (short)f2bf(a.z); r[3] = (short)f2bf(a.w);
    r[4] = (short)f2bf(b.x); r[5] = (short)f2bf(b.y);
    r[6] = (short)f2bf(b.z); r[7] = (short)f2bf(b.w);
    return r;
}

// conv segments in 8-element units (weights only; x/fc_in_W fused into GEMM)
#define T0 16384    // fc1Wb   [128,1024]
#define T1 16896    // Wb      [64,64]
#define T2 82432    // out1WbT [4096,128] row-permuted
#define T3 99328    // Gb      [2112,64] = tgw cols 0:64
#define CONV_BLOCKS 388   // T3/256

// ---------------------------------------------------------------------------
// Phase device functions (verbatim R3 cores, BK=32)
// ---------------------------------------------------------------------------
static __device__ __forceinline__ void conv_phase(
    int bx,
    const float* __restrict__ fc1W, const float* __restrict__ ntW,
    const float* __restrict__ out1W, const float* __restrict__ tgw,
    unsigned short* __restrict__ fc1Wb, unsigned short* __restrict__ Wb,
    unsigned short* __restrict__ out1WbT, unsigned short* __restrict__ Gb)
{
    int u = bx * 256 + threadIdx.x;
    if (u < T0) {
        int i8 = u * 8;
        *reinterpret_cast<bf16x8*>(&fc1Wb[i8]) = cvt8(&fc1W[i8]);
    } else if (u < T1) {
        int i8 = (u - T0) * 8;
        *reinterpret_cast<bf16x8*>(&Wb[i8]) = cvt8(&ntW[i8]);
    } else if (u < T2) {
        int i = u - T1;
        int n = i >> 4, kc = i & 15;
        int d = n >> 6, p = n & 63;
        *reinterpret_cast<bf16x8*>(&out1WbT[(size_t)n * 128 + kc * 8]) =
            cvt8(&out1W[(size_t)((p << 6) | d) * 128 + kc * 8]);
    } else if (u < T3) {
        int i = u - T2;
        int e = i >> 3, c = i & 7;
        *reinterpret_cast<bf16x8*>(&Gb[(size_t)e * 64 + c * 8]) =
            cvt8(&tgw[(size_t)e * 2112 + c * 8]);
    }
}

static __device__ __forceinline__ void coef_phase(
    int bx, float* __restrict__ smemf,
    const float* __restrict__ coef_m, const float* __restrict__ cW,
    const float* __restrict__ cB, const float* __restrict__ attW,
    float* __restrict__ cfs)
{
    float* cf_s = smemf;            // [4][256]
    float* part = smemf + 1024;     // [4][64]
    const int t = threadIdx.x;
    const int wv = t >> 6, lane = t & 63;
    const int xy = bx * 4 + wv;
    float ls = 0.0f;
    #pragma unroll
    for (int i = 0; i < 4; ++i) {
        int idx = i * 64 + lane;
        int f = idx >> 5;
        float v = fast_elu(coef_m[xy * 8 + f] * cW[idx] + cB[idx]);
        cf_s[wv * 256 + idx] = v;
        ls += __expf(fast_elu(v));
    }
    #pragma unroll
    for (int m = 1; m < 64; m <<= 1) ls += __shfl_xor(ls, m, 64);
    __syncthreads();
    const float rs = __builtin_amdgcn_rcpf(ls);
    const int g = lane & 31, fg = lane >> 5;
    float acc = 0.0f;
    for (int f = fg * 4; f < fg * 4 + 4; ++f) {
        float lin = 0.0f;
        #pragma unroll
        for (int h = 0; h < 32; h += 4) {
            float4 Lv = *reinterpret_cast<const float4*>(&cf_s[wv * 256 + f * 32 + h]);
            float4 Wv = *reinterpret_cast<const float4*>(&attW[f * 1024 + g * 32 + h]);
            lin += Lv.x * Wv.x + Lv.y * Wv.y + Lv.z * Wv.z + Lv.w * Wv.w;
        }
        float e = __expf(fast_elu(cf_s[wv * 256 + f * 32 + g]));
        acc += fast_elu(e * lin * rs);
    }
    part[wv * 64 + lane] = acc;
    __syncthreads();
    if (lane < 32) {
        float tot = part[wv * 64 + lane] + part[wv * 64 + lane + 32];
        cfs[xy * 32 + lane] = fast_elu(tot * 0.125f);
    }
}

// att phase emits bf16 (attb) — consumed only by the M1 GEMM.
static __device__ __forceinline__ void att_phase(
    int o, int ic, float* __restrict__ smemf,
    const float* __restrict__ cfs, const float* __restrict__ oattW,
    unsigned short* __restrict__ attb)
{
    float* L    = smemf;          // 2048
    float* red  = smemf + 2048;   // 256
    float* csum = smemf + 2304;   // 32
    const int t = threadIdx.x;
    #pragma unroll
    for (int j = 0; j < 8; ++j) L[t + 256 * j] = cfs[o * 2048 + t + 256 * j];
    __syncthreads();
    {
        int h = t & 31, ig = t >> 5;
        float ps = 0.0f;
        for (int i = ig * 8; i < ig * 8 + 8; ++i) ps += __expf(fast_elu(L[i * 32 + h]));
        red[t] = ps;
        __syncthreads();
        if (t < 32) {
            float cs = 0.0f;
            #pragma unroll
            for (int j = 0; j < 8; ++j) cs += red[j * 32 + t];
            csum[t] = cs;
        }
        __syncthreads();
    }
    int idx = ic * 256 + t;
    int i = idx >> 5, g = idx & 31;
    float lin2 = 0.0f;
    #pragma unroll
    for (int h = 0; h < 32; h += 4) {
        float4 Lv = *reinterpret_cast<const float4*>(&L[i * 32 + h]);
        float4 Wv = *reinterpret_cast<const float4*>(&oattW[i * 1024 + g * 32 + h]);
        lin2 += Lv.x * Wv.x + Lv.y * Wv.y + Lv.z * Wv.z + Lv.w * Wv.w;
    }
    float p2 = __expf(fast_elu(L[idx])) * __builtin_amdgcn_rcpf(csum[g]);
    attb[o * 2048 + idx] = f2bf(p2 * lin2);
}

// fc_in GEMM with f32 A/B and cvt fused into staging; K padded 2048, ksplit 4
static __device__ __forceinline__ void gemm_xfs_core(
    const float* __restrict__ A, const float* __restrict__ B,
    float* __restrict__ C, int ldc, long strideCz,
    int bn, int bm, int bz,
    unsigned short* __restrict__ As, unsigned short* __restrict__ Bs)
{
    const int t = threadIdx.x;
    const int w = t >> 6, lane = t & 63, l16 = lane & 15, quad = lane >> 4;
    const int n0 = bn * 64, m0 = bm * 64;
    const int kb0 = bz * 512;
    const int r = t >> 2, koff = (t & 3) * 8;
    C += (size_t)bz * strideCz;

    const float* arow = A + (size_t)(m0 + r) * 2000;
    const float* brow = B + (size_t)(n0 + r) * 2000;
    const bf16x8 zv = {0, 0, 0, 0, 0, 0, 0, 0};
    int k0 = kb0 + koff;
    bf16x8 av = (k0 < 2000) ? cvt8(arow + k0) : zv;
    bf16x8 bv = (k0 < 2000) ? cvt8(brow + k0) : zv;

    f32x4 acc[4] = {};
    for (int kb = kb0; kb < kb0 + 512; kb += 32) {
        __syncthreads();
        *reinterpret_cast<bf16x8*>(&As[r * 40 + koff]) = av;
        *reinterpret_cast<bf16x8*>(&Bs[r * 40 + koff]) = bv;
        if (kb + 32 < kb0 + 512) {
            int k = kb + 32 + koff;
            av = (k < 2000) ? cvt8(arow + k) : zv;
            bv = (k < 2000) ? cvt8(brow + k) : zv;
        }
        __syncthreads();
        bf16x8 af = *reinterpret_cast<const bf16x8*>(&As[(w * 16 + l16) * 40 + quad * 8]);
        #pragma unroll
        for (int nt = 0; nt < 4; ++nt) {
            bf16x8 bf = *reinterpret_cast<const bf16x8*>(&Bs[(nt * 16 + l16) * 40 + quad * 8]);
            acc[nt] = __builtin_amdgcn_mfma_f32_16x16x32_bf16(af, bf, acc[nt], 0, 0, 0);
        }
    }
    #pragma unroll
    for (int nt = 0; nt < 4; ++nt)
        #pragma unroll
        for (int i = 0; i < 4; ++i) {
            int m = m0 + w * 16 + quad * 4 + i;
            int n = n0 + nt * 16 + l16;
            C[(size_t)m * ldc + n] = acc[nt][i];
        }
}

// M1 GEMM: A = f32 tgw (cols 64..2112, cvt fused), B = attb [64,2048] bf16.
static __device__ __forceinline__ void gemm_tgwa_core(
    const float* __restrict__ tgw,
    const unsigned short* __restrict__ B,
    float* __restrict__ C, long strideCz,
    int kchunk, int bm, int bz,
    unsigned short* __restrict__ As, unsigned short* __restrict__ Bs)
{
    const int t = threadIdx.x;
    const int w = t >> 6, lane = t & 63, l16 = lane & 15, quad = lane >> 4;
    const int m0 = bm * 64;
    const int kb0 = bz * kchunk;
    const int r = t >> 2, koff = (t & 3) * 8;
    C += (size_t)bz * strideCz;

    const float* arow = tgw + (size_t)(m0 + r) * 2112 + 64 + koff;
    const unsigned short* brow = B + (size_t)r * 2048 + koff;
    bf16x8 av = cvt8(arow + kb0);
    bf16x8 bv = *reinterpret_cast<const bf16x8*>(brow + kb0);

    f32x4 acc[4] = {};
    for (int kb = kb0; kb < kb0 + kchunk; kb += 32) {
        __syncthreads();
        *reinterpret_cast<bf16x8*>(&As[r * 40 + koff]) = av;
        *reinterpret_cast<bf16x8*>(&Bs[r * 40 + koff]) = bv;
        if (kb + 32 < kb0 + kchunk) {
            av = cvt8(arow + kb + 32);
            bv = *reinterpret_cast<const bf16x8*>(brow + kb + 32);
        }
        __syncthreads();
        bf16x8 af = *reinterpret_cast<const bf16x8*>(&As[(w * 16 + l16) * 40 + quad * 8]);
        #pragma unroll
        for (int nt = 0; nt < 4; ++nt) {
            bf16x8 bf = *reinterpret_cast<const bf16x8*>(&Bs[(nt * 16 + l16) * 40 + quad * 8]);
            acc[nt] = __builtin_amdgcn_mfma_f32_16x16x32_bf16(af, bf, acc[nt], 0, 0, 0);
        }
    }
    #pragma unroll
    for (int nt = 0; nt < 4; ++nt)
        #pragma unroll
        for (int i = 0; i < 4; ++i) {
            int m = m0 + w * 16 + quad * 4 + i;
            int n = nt * 16 + l16;
            C[(size_t)m * 64 + n] = acc[nt][i];
        }
}

// GEMM with A from nparts f32 k-split partials: sum + abias + relu + cvt inline.
static __device__ __forceinline__ void gemm_fa_core(
    const float* __restrict__ Ap, int lda, long apstride, int nparts,
    const float* __restrict__ abias,
    const unsigned short* __restrict__ B, int ldb,
    float* __restrict__ C, unsigned short* __restrict__ Cb,
    int ldc, long strideCz, const float* __restrict__ bias,
    int mode, int kchunk, int bn, int bm, int bz,
    unsigned short* __restrict__ As, unsigned short* __restrict__ Bs)
{
    const int t = threadIdx.x;
    const int w = t >> 6, lane = t & 63, l16 = lane & 15, quad = lane >> 4;
    const int n0 = bn * 64, m0 = bm * 64;
    const int kb0 = bz * kchunk;
    const int r = t >> 2, koff = (t & 3) * 8;
    if (mode == 0) C += (size_t)bz * strideCz;

    f32x4 acc[4] = {};
    for (int kb = kb0; kb < kb0 + kchunk; kb += 32) {
        float a8[8];
        {
            const float* base = &Ap[(size_t)(m0 + r) * lda + kb + koff];
            float4 s0 = *reinterpret_cast<const float4*>(base);
            float4 s1 = *reinterpret_cast<const float4*>(base + 4);
            for (int j = 1; j < nparts; ++j) {
                const float* pj = base + (size_t)j * apstride;
                float4 p0 = *reinterpret_cast<const float4*>(pj);
                float4 p1 = *reinterpret_cast<const float4*>(pj + 4);
                s0.x += p0.x; s0.y += p0.y; s0.z += p0.z; s0.w += p0.w;
                s1.x += p1.x; s1.y += p1.y; s1.z += p1.z; s1.w += p1.w;
            }
            float4 b0 = *reinterpret_cast<const float4*>(&abias[kb + koff]);
            float4 b1 = *reinterpret_cast<const float4*>(&abias[kb + koff + 4]);
            a8[0] = fmaxf(s0.x + b0.x, 0.0f); a8[1] = fmaxf(s0.y + b0.y, 0.0f);
            a8[2] = fmaxf(s0.z + b0.z, 0.0f); a8[3] = fmaxf(s0.w + b0.w, 0.0f);
            a8[4] = fmaxf(s1.x + b1.x, 0.0f); a8[5] = fmaxf(s1.y + b1.y, 0.0f);
            a8[6] = fmaxf(s1.z + b1.z, 0.0f); a8[7] = fmaxf(s1.w + b1.w, 0.0f);
        }
        bf16x8 bv = *reinterpret_cast<const bf16x8*>(&B[(size_t)(n0 + r) * ldb + kb + koff]);
        __syncthreads();
        ushort4 lo, hi;
        lo.x = f2bf(a8[0]); lo.y = f2bf(a8[1]); lo.z = f2bf(a8[2]); lo.w = f2bf(a8[3]);
        hi.x = f2bf(a8[4]); hi.y = f2bf(a8[5]); hi.z = f2bf(a8[6]); hi.w = f2bf(a8[7]);
        *reinterpret_cast<ushort4*>(&As[r * 40 + koff]) = lo;
        *reinterpret_cast<ushort4*>(&As[r * 40 + koff + 4]) = hi;
        *reinterpret_cast<bf16x8*>(&Bs[r * 40 + koff]) = bv;
        __syncthreads();
        bf16x8 af = *reinterpret_cast<const bf16x8*>(&As[(w * 16 + l16) * 40 + quad * 8]);
        #pragma unroll
        for (int nt = 0; nt < 4; ++nt) {
            bf16x8 bf = *reinterpret_cast<const bf16x8*>(&Bs[(nt * 16 + l16) * 40 + quad * 8]);
            acc[nt] = __builtin_amdgcn_mfma_f32_16x16x32_bf16(af, bf, acc[nt], 0, 0, 0);
        }
    }
    #pragma unroll
    for (int nt = 0; nt < 4; ++nt)
        #pragma unroll
        for (int i = 0; i < 4; ++i) {
            int m = m0 + w * 16 + quad * 4 + i;
            int n = n0 + nt * 16 + l16;
            if (mode == 0) {
                C[(size_t)m * ldc + n] = acc[nt][i];
            } else {
                int bidx = (((n & 63) << 6) | (n >> 6));
                float v = acc[nt][i] + bias[bidx];
                v = fmaxf(v, 0.0f);
                Cb[(size_t)m * ldc + n] = f2bf(v);
            }
        }
}

// cmat-small: cmat[e,o] = sum_p M1[e,p] * ntW[o,p]; M1 summed from 8 cpT
// partials inline (K=64, 2 MFMA steps). Writes cmatT [2112][64] f32.
static __device__ __forceinline__ void cmat_small_core(
    const float* __restrict__ Ap,
    const unsigned short* __restrict__ Wb,
    float* __restrict__ cmatT, int bm,
    unsigned short* __restrict__ As, unsigned short* __restrict__ Bs)
{
    const int t = threadIdx.x;
    const int w = t >> 6, lane = t & 63, l16 = lane & 15, quad = lane >> 4;
    const int m0 = bm * 64;
    const int r = t >> 2, koff = (t & 3) * 8;

    f32x4 acc[4] = {};
    for (int kb = 0; kb < 64; kb += 32) {
        float a8[8];
        {
            const float* base = &Ap[(size_t)(m0 + r) * 64 + kb + koff];
            float4 s0 = *reinterpret_cast<const float4*>(base);
            float4 s1 = *reinterpret_cast<const float4*>(base + 4);
            #pragma unroll
            for (int j = 1; j < 8; ++j) {
                const float* pj = base + (size_t)j * 135168L;
                float4 p0 = *reinterpret_cast<const float4*>(pj);
                float4 p1 = *reinterpret_cast<const float4*>(pj + 4);
                s0.x += p0.x; s0.y += p0.y; s0.z += p0.z; s0.w += p0.w;
                s1.x += p1.x; s1.y += p1.y; s1.z += p1.z; s1.w += p1.w;
            }
            a8[0] = s0.x; a8[1] = s0.y; a8[2] = s0.z; a8[3] = s0.w;
            a8[4] = s1.x; a8[5] = s1.y; a8[6] = s1.z; a8[7] = s1.w;
        }
        bf16x8 bv = *reinterpret_cast<const bf16x8*>(&Wb[(size_t)r * 64 + kb + koff]);
        __syncthreads();
        ushort4 lo, hi;
        lo.x = f2bf(a8[0]); lo.y = f2bf(a8[1]); lo.z = f2bf(a8[2]); lo.w = f2bf(a8[3]);
        hi.x = f2bf(a8[4]); hi.y = f2bf(a8[5]); hi.z = f2bf(a8[6]); hi.w = f2bf(a8[7]);
        *reinterpret_cast<ushort4*>(&As[r * 40 + koff]) = lo;
        *reinterpret_cast<ushort4*>(&As[r * 40 + koff + 4]) = hi;
        *reinterpret_cast<bf16x8*>(&Bs[r * 40 + koff]) = bv;
        __syncthreads();
        bf16x8 af = *reinterpret_cast<const bf16x8*>(&As[(w * 16 + l16) * 40 + quad * 8]);
        #pragma unroll
        for (int nt = 0; nt < 4; ++nt) {
            bf16x8 bf = *reinterpret_cast<const bf16x8*>(&Bs[(nt * 16 + l16) * 40 + quad * 8]);
            acc[nt] = __builtin_amdgcn_mfma_f32_16x16x32_bf16(af, bf, acc[nt], 0, 0, 0);
        }
    }
    #pragma unroll
    for (int nt = 0; nt < 4; ++nt)
        #pragma unroll
        for (int i = 0; i < 4; ++i) {
            int m = m0 + w * 16 + quad * 4 + i;   // e
            int n = nt * 16 + l16;                // o
            cmatT[(size_t)m * 64 + n] = acc[nt][i];
        }
}

static __device__ __forceinline__ void nt1f_phase(
    int b, unsigned short* __restrict__ smemu,
    const unsigned short* __restrict__ hbT, const unsigned short* __restrict__ Wb,
    unsigned short* __restrict__ nt1b)
{
    unsigned short* HtT   = smemu;             // [64][72]
    unsigned short* nt1_s = smemu + 64 * 72;   // [64][72]
    const int t = threadIdx.x;
    const int w = t >> 6, lane = t & 63, l16 = lane & 15, quad = lane >> 4;

    const unsigned short* src = hbT + (size_t)b * 4096;
    #pragma unroll
    for (int j = 0; j < 2; ++j) {
        int c = t + j * 256;
        *reinterpret_cast<bf16x8*>(&HtT[(c >> 3) * 72 + (c & 7) * 8]) =
            *reinterpret_cast<const bf16x8*>(&src[c * 8]);
    }
    __syncthreads();

    bf16x8 aW[2];
    #pragma unroll
    for (int h = 0; h < 2; ++h)
        aW[h] = *reinterpret_cast<const bf16x8*>(&Wb[(w * 16 + l16) * 64 + h * 32 + quad * 8]);
    #pragma unroll
    for (int dt = 0; dt < 4; ++dt) {
        f32x4 acc = {0.0f, 0.0f, 0.0f, 0.0f};
        #pragma unroll
        for (int h = 0; h < 2; ++h) {
            bf16x8 bf = *reinterpret_cast<const bf16x8*>(
                &HtT[(dt * 16 + l16) * 72 + h * 32 + quad * 8]);
            acc = __builtin_amdgcn_mfma_f32_16x16x32_bf16(aW[h], bf, acc, 0, 0, 0);
        }
        #pragma unroll
        for (int i = 0; i < 4; ++i)
            nt1_s[(w * 16 + quad * 4 + i) * 72 + dt * 16 + l16] = f2bf(acc[i]);
    }
    __syncthreads();
    #pragma unroll
    for (int j = 0; j < 2; ++j) {
        int c = t + j * 256;
        *reinterpret_cast<bf16x8*>(&nt1b[(size_t)b * 4096 + c * 8]) =
            *reinterpret_cast<const bf16x8*>(&nt1_s[(c >> 3) * 72 + (c & 7) * 8]);
    }
}

// final: barrier-free, LDS-free. One unit = (eb, 16-batch group at b0).
static __device__ __forceinline__ void final_phase(
    int eb, int b0,
    const unsigned short* __restrict__ nt1b,
    const unsigned short* __restrict__ Gb,
    const float* __restrict__ cmatT,
    const float* __restrict__ outW,
    float* __restrict__ zpart)
{
    const int t = threadIdx.x;
    const int w = t >> 6, lane = t & 63, l16 = lane & 15, quad = lane >> 4;
    const int o = w * 16 + l16;

    bf16x8 ga[4][2];
    float cm[4][4], wv[4][4];
    #pragma unroll
    for (int et = 0; et < 4; ++et) {
        #pragma unroll
        for (int h = 0; h < 2; ++h)
            ga[et][h] = *reinterpret_cast<const bf16x8*>(
                &Gb[(size_t)(eb * 64 + et * 16 + l16) * 64 + h * 32 + quad * 8]);
        #pragma unroll
        for (int i = 0; i < 4; ++i) {
            int e = eb * 64 + et * 16 + quad * 4 + i;
            cm[et][i] = cmatT[(size_t)e * 64 + o];
            wv[et][i] = outW[e];
        }
    }

    const unsigned short* bbase = nt1b + (size_t)b0 * 4096 + o * 64 + quad * 8;
    bf16x8 bf0 = *reinterpret_cast<const bf16x8*>(bbase);
    bf16x8 bf1 = *reinterpret_cast<const bf16x8*>(bbase + 32);

    for (int bi = 0; bi < 16; ++bi) {
        bf16x8 nb0, nb1;
        if (bi < 15) {
            nb0 = *reinterpret_cast<const bf16x8*>(bbase + (size_t)(bi + 1) * 4096);
            nb1 = *reinterpret_cast<const bf16x8*>(bbase + (size_t)(bi + 1) * 4096 + 32);
        }
        float zo = 0.0f;
        #pragma unroll
        for (int et = 0; et < 4; ++et) {
            f32x4 acc = {cm[et][0], cm[et][1], cm[et][2], cm[et][3]};
            acc = __builtin_amdgcn_mfma_f32_16x16x32_bf16(ga[et][0], bf0, acc, 0, 0, 0);
            acc = __builtin_amdgcn_mfma_f32_16x16x32_bf16(ga[et][1], bf1, acc, 0, 0, 0);
            #pragma unroll
            for (int i = 0; i < 4; ++i)
                zo += __builtin_amdgcn_rcpf(1.0f + __expf(-acc[i])) * wv[et][i];
        }
        zo += __shfl_xor(zo, 16, 64);
        zo += __shfl_xor(zo, 32, 64);
        if (quad == 0)
            zpart[((size_t)eb * 512 + b0 + bi) * 64 + o] = zo;
        bf0 = nb0; bf1 = nb1;
    }
}

static __device__ __forceinline__ void finish_phase(
    int fb, const float* __restrict__ zpart, const float* __restrict__ outB,
    const float* __restrict__ preluA, float* __restrict__ out)
{
    int i = fb * 256 + threadIdx.x;  // < 32768
    float z = 0.0f;
    for (int j = 0; j < 33; ++j) z += zpart[(size_t)j * 32768 + i];
    z += outB[0];
    float pa = preluA[0];
    out[i] = (z >= 0.0f) ? z : pa * z;
}

// ---------------------------------------------------------------------------
// Mega cooperative kernel: 6 phases, 5 grid syncs, grid 512 x 256.
// __launch_bounds__(256, 2): 2 blocks/CU guaranteed -> 512 co-resident.
// ---------------------------------------------------------------------------
__global__ __launch_bounds__(256, 2) void mega(
    const float* x, const float* fcinW, const float* fc_in_b,
    const float* fc1W, const float* fc1_b,
    const float* out1W, const float* out1_b,
    const float* cW, const float* cB, const float* cattW, const float* oattW,
    const float* ntW, const float* tgw, const float* outW, const float* outB,
    const float* preluA, const float* coef_m,
    float* out,
    unsigned short* fc1Wb, unsigned short* Wb, unsigned short* out1WbT,
    unsigned short* Gb, float* cfs, unsigned short* attb,
    float* h1p, float* h2p, unsigned short* hbT, float* cpT, float* cmatT,
    unsigned short* nt1b, float* zpart)
{
    cg::grid_group grid = cg::this_grid();
    __shared__ __align__(16) float smemf[4608];
    unsigned short* As = (unsigned short*)smemf;
    const int b = blockIdx.x;   // 0..511

    // ---- P1: conv (b<388) + fc_in GEMM (all) + coef (2 units each) ----
    if (b < CONV_BLOCKS)
        conv_phase(b, fc1W, ntW, out1W, tgw, fc1Wb, Wb, out1WbT, Gb);
    gemm_xfs_core(x, fcinW, h1p, 1024, 524288L,
                  b & 15, (b >> 4) & 7, b >> 7, As, As + 2560);
    __syncthreads();
    coef_phase(b, smemf, coef_m, cW, cB, cattW, cfs);
    __syncthreads();
    coef_phase(b + 512, smemf, coef_m, cW, cB, cattW, cfs);
    grid.sync();

    // ---- P2: att (all) + fc1 GEMM(fa) (b<64) ----
    att_phase(b & 63, b >> 6, smemf, cfs, oattW, attb);
    if (b < 64) {
        __syncthreads();
        gemm_fa_core(h1p, 1024, 524288L, 4, fc_in_b, fc1Wb, 1024,
                     h2p, nullptr, 128, 65536L, nullptr, 0, 256,
                     b & 1, (b >> 1) & 7, b >> 4, As, As + 2560);
    }
    grid.sync();

    // ---- P3: out1 GEMM(fa) (all) + M1 GEMM (b<264) ----
    gemm_fa_core(h2p, 128, 65536L, 4, fc1_b, out1WbT, 128,
                 nullptr, hbT, 4096, 0L, out1_b, 2, 128,
                 b & 63, b >> 6, 0, As, As + 2560);
    if (b < 264) {
        __syncthreads();
        gemm_tgwa_core(tgw, attb, cpT, 135168L, 256,
                       b % 33, b / 33, As, As + 2560);
    }
    grid.sync();

    // ---- P4: nt1f (all) + cmat-small (b<33) ----
    nt1f_phase(b, (unsigned short*)smemf, hbT, Wb, nt1b);
    if (b < 33) {
        __syncthreads();
        cmat_small_core(cpT, Wb, cmatT, b, As, As + 2560);
    }
    grid.sync();

    // ---- P5: final (1056 units over 512 blocks) ----
    {
        final_phase(b % 33, (b / 33) * 16, nt1b, Gb, cmatT, outW, zpart);
        int u = b + 512;
        final_phase(u % 33, (u / 33) * 16, nt1b, Gb, cmatT, outW, zpart);
        if (b < 32) {
            int u2 = b + 1024;
            final_phase(u2 % 33, (u2 / 33) * 16, nt1b, Gb, cmatT, outW, zpart);
        }
    }
    grid.sync();

    // ---- P6: finish (b<128) ----
    if (b < 128)
        finish_phase(b, zpart, outB, preluA, out);
}

extern "C" void kernel_launch(void* const* d_in, const int* in_sizes, int n_in,
                              void* d_out, int out_size, void* d_ws, size_t ws_size,
                              hipStream_t stream)
{
    const float* x       = (const float*)d_in[0];
    const float* fc_in_W = (const float*)d_in[1];
    const float* fc_in_b = (const float*)d_in[2];
    const float* fc1_W   = (const float*)d_in[3];
    const float* fc1_b   = (const float*)d_in[4];
    const float* out1_W  = (const float*)d_in[5];
    const float* out1_b  = (const float*)d_in[6];
    const float* cW      = (const float*)d_in[7];
    const float* cB      = (const float*)d_in[8];
    const float* cattW   = (const float*)d_in[9];
    const float* oattW   = (const float*)d_in[10];
    const float* ntW     = (const float*)d_in[11];
    const float* tgw     = (const float*)d_in[12];
    const float* outW    = (const float*)d_in[13];
    const float* outB    = (const float*)d_in[14];
    const float* preluA  = (const float*)d_in[15];
    const float* coef_m  = (const float*)d_in[16];
    float* out = (float*)d_out;
    float* ws  = (float*)d_ws;

    // workspace layout (float offsets) — no aliasing (~29.4 MB)
    unsigned short* fc1Wb   = (unsigned short*)(ws + 0);          // 65,536 f
    unsigned short* Wb      = (unsigned short*)(ws + 65536);      // 2,048 f
    unsigned short* out1WbT = (unsigned short*)(ws + 67584);      // 262,144 f
    unsigned short* Gb      = (unsigned short*)(ws + 329728);     // 67,584 f
    float*          cfs     = ws + 397312;                        // 131,072 f
    unsigned short* attb    = (unsigned short*)(ws + 528384);     // 65,536 f
    float*          h1p     = ws + 593920;                        // 4*524,288 f
    float*          h2p     = ws + 2691072;                       // 4*65,536 f
    unsigned short* hbT     = (unsigned short*)(ws + 2953216);    // 1,048,576 f
    float*          cpT     = ws + 4001792;                       // 8*135,168 f
    float*          cmatT   = ws + 5083136;                       // 135,168 f
    unsigned short* nt1b    = (unsigned short*)(ws + 5218304);    // 1,048,576 f
    float*          zpart   = ws + 6266880;                       // 1,081,344 f
    // total 7,348,224 floats

    void* kargs[] = {
        (void*)&x, (void*)&fc_in_W, (void*)&fc_in_b,
        (void*)&fc1_W, (void*)&fc1_b,
        (void*)&out1_W, (void*)&out1_b,
        (void*)&cW, (void*)&cB, (void*)&cattW, (void*)&oattW,
        (void*)&ntW, (void*)&tgw, (void*)&outW, (void*)&outB,
        (void*)&preluA, (void*)&coef_m,
        (void*)&out,
        (void*)&fc1Wb, (void*)&Wb, (void*)&out1WbT,
        (void*)&Gb, (void*)&cfs, (void*)&attb,
        (void*)&h1p, (void*)&h2p, (void*)&hbT, (void*)&cpT, (void*)&cmatT,
        (void*)&nt1b, (void*)&zpart
    };
    hipLaunchCooperativeKernel((const void*)mega, dim3(512), dim3(256),
                               kargs, 0, stream);
}

// Round 6
// 184.613 us; speedup vs baseline: 2.6570x; 2.6570x over previous
//
#include <hip/hip_runtime.h>
#include <math.h>

typedef __attribute__((ext_vector_type(8))) short bf16x8;
typedef __attribute__((ext_vector_type(4))) float f32x4;

static __device__ __forceinline__ float fast_elu(float x) {
    return x > 0.0f ? x : __expf(x) - 1.0f;
}

static __device__ __forceinline__ unsigned short f2bf(float f) {
    unsigned int u = __float_as_uint(f);
    unsigned int r = (u + 0x7FFFu + ((u >> 16) & 1u)) >> 16;
    return (unsigned short)r;
}

static __device__ __forceinline__ bf16x8 cvt8(const float* __restrict__ s) {
    float4 a = *reinterpret_cast<const float4*>(s);
    float4 b = *reinterpret_cast<const float4*>(s + 4);
    bf16x8 r;
    r[0] = (short)f2bf(a.x); r[1] = (short)f2bf(a.y);
    r[2] = (short)f2bf(a.z); r[3] = (short)f2bf(a.w);
    r[4] = (short)f2bf(b.x); r[5] = (short)f2bf(b.y);
    r[6] = (short)f2bf(b.z); r[7] = (short)f2bf(b.w);
    return r;
}

// conv segments in 8-element units (weights only; x/fc_in_W fused into GEMM)
#define T0 16384    // fc1Wb   [128,1024]
#define T1 16896    // Wb      [64,64]
#define T2 82432    // out1WbT [4096,128] row-permuted
#define T3 99328    // Gb      [2112,64] = tgw cols 0:64
#define CONV_BLOCKS 388   // T3/256

// ---------------------------------------------------------------------------
// Phase device functions
// ---------------------------------------------------------------------------
static __device__ __forceinline__ void conv_phase(
    int bx,
    const float* __restrict__ fc1W, const float* __restrict__ ntW,
    const float* __restrict__ out1W, const float* __restrict__ tgw,
    unsigned short* __restrict__ fc1Wb, unsigned short* __restrict__ Wb,
    unsigned short* __restrict__ out1WbT, unsigned short* __restrict__ Gb)
{
    int u = bx * 256 + threadIdx.x;
    if (u < T0) {
        int i8 = u * 8;
        *reinterpret_cast<bf16x8*>(&fc1Wb[i8]) = cvt8(&fc1W[i8]);
    } else if (u < T1) {
        int i8 = (u - T0) * 8;
        *reinterpret_cast<bf16x8*>(&Wb[i8]) = cvt8(&ntW[i8]);
    } else if (u < T2) {
        int i = u - T1;
        int n = i >> 4, kc = i & 15;
        int d = n >> 6, p = n & 63;
        *reinterpret_cast<bf16x8*>(&out1WbT[(size_t)n * 128 + kc * 8]) =
            cvt8(&out1W[(size_t)((p << 6) | d) * 128 + kc * 8]);
    } else if (u < T3) {
        int i = u - T2;
        int e = i >> 3, c = i & 7;
        *reinterpret_cast<bf16x8*>(&Gb[(size_t)e * 64 + c * 8]) =
            cvt8(&tgw[(size_t)e * 2112 + c * 8]);
    }
}

static __device__ __forceinline__ void coef_phase(
    int bx, float* __restrict__ smemf,
    const float* __restrict__ coef_m, const float* __restrict__ cW,
    const float* __restrict__ cB, const float* __restrict__ attW,
    float* __restrict__ cfs)
{
    float* cf_s = smemf;            // [4][256]
    float* part = smemf + 1024;     // [4][64]
    const int t = threadIdx.x;
    const int wv = t >> 6, lane = t & 63;
    const int xy = bx * 4 + wv;
    float ls = 0.0f;
    #pragma unroll
    for (int i = 0; i < 4; ++i) {
        int idx = i * 64 + lane;
        int f = idx >> 5;
        float v = fast_elu(coef_m[xy * 8 + f] * cW[idx] + cB[idx]);
        cf_s[wv * 256 + idx] = v;
        ls += __expf(fast_elu(v));
    }
    #pragma unroll
    for (int m = 1; m < 64; m <<= 1) ls += __shfl_xor(ls, m, 64);
    __syncthreads();
    const float rs = __builtin_amdgcn_rcpf(ls);
    const int g = lane & 31, fg = lane >> 5;
    float acc = 0.0f;
    for (int f = fg * 4; f < fg * 4 + 4; ++f) {
        float lin = 0.0f;
        #pragma unroll
        for (int h = 0; h < 32; h += 4) {
            float4 Lv = *reinterpret_cast<const float4*>(&cf_s[wv * 256 + f * 32 + h]);
            float4 Wv = *reinterpret_cast<const float4*>(&attW[f * 1024 + g * 32 + h]);
            lin += Lv.x * Wv.x + Lv.y * Wv.y + Lv.z * Wv.z + Lv.w * Wv.w;
        }
        float e = __expf(fast_elu(cf_s[wv * 256 + f * 32 + g]));
        acc += fast_elu(e * lin * rs);
    }
    part[wv * 64 + lane] = acc;
    __syncthreads();
    if (lane < 32) {
        float tot = part[wv * 64 + lane] + part[wv * 64 + lane + 32];
        cfs[xy * 32 + lane] = fast_elu(tot * 0.125f);
    }
}

// att phase emits bf16 (attb) — consumed only by the M1 GEMM.
static __device__ __forceinline__ void att_phase(
    int o, int ic, float* __restrict__ smemf,
    const float* __restrict__ cfs, const float* __restrict__ oattW,
    unsigned short* __restrict__ attb)
{
    float* L    = smemf;          // 2048
    float* red  = smemf + 2048;   // 256
    float* csum = smemf + 2304;   // 32
    const int t = threadIdx.x;
    #pragma unroll
    for (int j = 0; j < 8; ++j) L[t + 256 * j] = cfs[o * 2048 + t + 256 * j];
    __syncthreads();
    {
        int h = t & 31, ig = t >> 5;
        float ps = 0.0f;
        for (int i = ig * 8; i < ig * 8 + 8; ++i) ps += __expf(fast_elu(L[i * 32 + h]));
        red[t] = ps;
        __syncthreads();
        if (t < 32) {
            float cs = 0.0f;
            #pragma unroll
            for (int j = 0; j < 8; ++j) cs += red[j * 32 + t];
            csum[t] = cs;
        }
        __syncthreads();
    }
    int idx = ic * 256 + t;
    int i = idx >> 5, g = idx & 31;
    float lin2 = 0.0f;
    #pragma unroll
    for (int h = 0; h < 32; h += 4) {
        float4 Lv = *reinterpret_cast<const float4*>(&L[i * 32 + h]);
        float4 Wv = *reinterpret_cast<const float4*>(&oattW[i * 1024 + g * 32 + h]);
        lin2 += Lv.x * Wv.x + Lv.y * Wv.y + Lv.z * Wv.z + Lv.w * Wv.w;
    }
    float p2 = __expf(fast_elu(L[idx])) * __builtin_amdgcn_rcpf(csum[g]);
    attb[o * 2048 + idx] = f2bf(p2 * lin2);
}

// fc_in GEMM with f32 A/B and cvt fused into staging; K padded 2048, ksplit 4
// (kchunk 512, 8-elem mask k<2000). 2-deep register prefetch.
static __device__ __forceinline__ void gemm_xfs_core(
    const float* __restrict__ A, const float* __restrict__ B,
    float* __restrict__ C, int ldc, long strideCz,
    int bn, int bm, int bz,
    unsigned short* __restrict__ As, unsigned short* __restrict__ Bs)
{
    const int t = threadIdx.x;
    const int w = t >> 6, lane = t & 63, l16 = lane & 15, quad = lane >> 4;
    const int n0 = bn * 64, m0 = bm * 64;
    const int kb0 = bz * 512;
    const int r = t >> 2, koff = (t & 3) * 8;
    C += (size_t)bz * strideCz;

    const float* arow = A + (size_t)(m0 + r) * 2000;
    const float* brow = B + (size_t)(n0 + r) * 2000;
    const bf16x8 zv = {0, 0, 0, 0, 0, 0, 0, 0};
    int k0 = kb0 + koff;
    bf16x8 av0 = (k0 < 2000) ? cvt8(arow + k0) : zv;
    bf16x8 bv0 = (k0 < 2000) ? cvt8(brow + k0) : zv;
    bf16x8 av1 = (k0 + 32 < 2000) ? cvt8(arow + k0 + 32) : zv;
    bf16x8 bv1 = (k0 + 32 < 2000) ? cvt8(brow + k0 + 32) : zv;

    f32x4 acc[4] = {};
    for (int kb = kb0; kb < kb0 + 512; kb += 32) {
        __syncthreads();
        *reinterpret_cast<bf16x8*>(&As[r * 40 + koff]) = av0;
        *reinterpret_cast<bf16x8*>(&Bs[r * 40 + koff]) = bv0;
        av0 = av1; bv0 = bv1;
        if (kb + 64 < kb0 + 512) {
            int k = kb + 64 + koff;
            av1 = (k < 2000) ? cvt8(arow + k) : zv;
            bv1 = (k < 2000) ? cvt8(brow + k) : zv;
        }
        __syncthreads();
        bf16x8 af = *reinterpret_cast<const bf16x8*>(&As[(w * 16 + l16) * 40 + quad * 8]);
        #pragma unroll
        for (int nt = 0; nt < 4; ++nt) {
            bf16x8 bf = *reinterpret_cast<const bf16x8*>(&Bs[(nt * 16 + l16) * 40 + quad * 8]);
            acc[nt] = __builtin_amdgcn_mfma_f32_16x16x32_bf16(af, bf, acc[nt], 0, 0, 0);
        }
    }
    #pragma unroll
    for (int nt = 0; nt < 4; ++nt)
        #pragma unroll
        for (int i = 0; i < 4; ++i) {
            int m = m0 + w * 16 + quad * 4 + i;
            int n = n0 + nt * 16 + l16;
            C[(size_t)m * ldc + n] = acc[nt][i];
        }
}

// M1 GEMM: A = f32 tgw (cols 64..2112, cvt fused), B = attb [64,2048] bf16.
// 2-deep register prefetch.
static __device__ __forceinline__ void gemm_tgwa_core(
    const float* __restrict__ tgw,
    const unsigned short* __restrict__ B,
    float* __restrict__ C, long strideCz,
    int kchunk, int bm, int bz,
    unsigned short* __restrict__ As, unsigned short* __restrict__ Bs)
{
    const int t = threadIdx.x;
    const int w = t >> 6, lane = t & 63, l16 = lane & 15, quad = lane >> 4;
    const int m0 = bm * 64;
    const int kb0 = bz * kchunk;
    const int r = t >> 2, koff = (t & 3) * 8;
    C += (size_t)bz * strideCz;

    const float* arow = tgw + (size_t)(m0 + r) * 2112 + 64 + koff;
    const unsigned short* brow = B + (size_t)r * 2048 + koff;
    bf16x8 av0 = cvt8(arow + kb0);
    bf16x8 bv0 = *reinterpret_cast<const bf16x8*>(brow + kb0);
    bf16x8 av1 = cvt8(arow + kb0 + 32);
    bf16x8 bv1 = *reinterpret_cast<const bf16x8*>(brow + kb0 + 32);

    f32x4 acc[4] = {};
    for (int kb = kb0; kb < kb0 + kchunk; kb += 32) {
        __syncthreads();
        *reinterpret_cast<bf16x8*>(&As[r * 40 + koff]) = av0;
        *reinterpret_cast<bf16x8*>(&Bs[r * 40 + koff]) = bv0;
        av0 = av1; bv0 = bv1;
        if (kb + 64 < kb0 + kchunk) {
            av1 = cvt8(arow + kb + 64);
            bv1 = *reinterpret_cast<const bf16x8*>(brow + kb + 64);
        }
        __syncthreads();
        bf16x8 af = *reinterpret_cast<const bf16x8*>(&As[(w * 16 + l16) * 40 + quad * 8]);
        #pragma unroll
        for (int nt = 0; nt < 4; ++nt) {
            bf16x8 bf = *reinterpret_cast<const bf16x8*>(&Bs[(nt * 16 + l16) * 40 + quad * 8]);
            acc[nt] = __builtin_amdgcn_mfma_f32_16x16x32_bf16(af, bf, acc[nt], 0, 0, 0);
        }
    }
    #pragma unroll
    for (int nt = 0; nt < 4; ++nt)
        #pragma unroll
        for (int i = 0; i < 4; ++i) {
            int m = m0 + w * 16 + quad * 4 + i;
            int n = nt * 16 + l16;
            C[(size_t)m * 64 + n] = acc[nt][i];
        }
}

// A-staging helper for gemm_fa: sum nparts f32 partials + bias + relu.
static __device__ __forceinline__ void fa_stage(
    const float* __restrict__ base, long apstride, int nparts,
    const float* __restrict__ ab, float a8[8])
{
    float4 s0 = *reinterpret_cast<const float4*>(base);
    float4 s1 = *reinterpret_cast<const float4*>(base + 4);
    for (int j = 1; j < nparts; ++j) {
        const float* pj = base + (size_t)j * apstride;
        float4 p0 = *reinterpret_cast<const float4*>(pj);
        float4 p1 = *reinterpret_cast<const float4*>(pj + 4);
        s0.x += p0.x; s0.y += p0.y; s0.z += p0.z; s0.w += p0.w;
        s1.x += p1.x; s1.y += p1.y; s1.z += p1.z; s1.w += p1.w;
    }
    float4 b0 = *reinterpret_cast<const float4*>(ab);
    float4 b1 = *reinterpret_cast<const float4*>(ab + 4);
    a8[0] = fmaxf(s0.x + b0.x, 0.0f); a8[1] = fmaxf(s0.y + b0.y, 0.0f);
    a8[2] = fmaxf(s0.z + b0.z, 0.0f); a8[3] = fmaxf(s0.w + b0.w, 0.0f);
    a8[4] = fmaxf(s1.x + b1.x, 0.0f); a8[5] = fmaxf(s1.y + b1.y, 0.0f);
    a8[6] = fmaxf(s1.z + b1.z, 0.0f); a8[7] = fmaxf(s1.w + b1.w, 0.0f);
}

// GEMM with A from nparts f32 k-split partials: sum + abias + relu + cvt inline.
// 2-deep register prefetch.
// mode 0: f32 partial -> C + bz*strideCz ; mode 2: bf16 relu(acc+bias[perm]) -> Cb
static __device__ __forceinline__ void gemm_fa_core(
    const float* __restrict__ Ap, int lda, long apstride, int nparts,
    const float* __restrict__ abias,
    const unsigned short* __restrict__ B, int ldb,
    float* __restrict__ C, unsigned short* __restrict__ Cb,
    int ldc, long strideCz, const float* __restrict__ bias,
    int mode, int kchunk, int bn, int bm, int bz,
    unsigned short* __restrict__ As, unsigned short* __restrict__ Bs)
{
    const int t = threadIdx.x;
    const int w = t >> 6, lane = t & 63, l16 = lane & 15, quad = lane >> 4;
    const int n0 = bn * 64, m0 = bm * 64;
    const int kb0 = bz * kchunk;
    const int r = t >> 2, koff = (t & 3) * 8;
    if (mode == 0) C += (size_t)bz * strideCz;

    const float* abase = &Ap[(size_t)(m0 + r) * lda + koff];
    const unsigned short* brow = &B[(size_t)(n0 + r) * ldb + koff];

    float a8_0[8], a8_1[8];
    fa_stage(abase + kb0, apstride, nparts, &abias[kb0 + koff], a8_0);
    bf16x8 bv0 = *reinterpret_cast<const bf16x8*>(brow + kb0);
    fa_stage(abase + kb0 + 32, apstride, nparts, &abias[kb0 + koff + 32], a8_1);
    bf16x8 bv1 = *reinterpret_cast<const bf16x8*>(brow + kb0 + 32);

    f32x4 acc[4] = {};
    for (int kb = kb0; kb < kb0 + kchunk; kb += 32) {
        __syncthreads();
        ushort4 lo, hi;
        lo.x = f2bf(a8_0[0]); lo.y = f2bf(a8_0[1]); lo.z = f2bf(a8_0[2]); lo.w = f2bf(a8_0[3]);
        hi.x = f2bf(a8_0[4]); hi.y = f2bf(a8_0[5]); hi.z = f2bf(a8_0[6]); hi.w = f2bf(a8_0[7]);
        *reinterpret_cast<ushort4*>(&As[r * 40 + koff]) = lo;
        *reinterpret_cast<ushort4*>(&As[r * 40 + koff + 4]) = hi;
        *reinterpret_cast<bf16x8*>(&Bs[r * 40 + koff]) = bv0;
        #pragma unroll
        for (int q = 0; q < 8; ++q) a8_0[q] = a8_1[q];
        bv0 = bv1;
        if (kb + 64 < kb0 + kchunk) {
            fa_stage(abase + kb + 64, apstride, nparts, &abias[kb + 64 + koff], a8_1);
            bv1 = *reinterpret_cast<const bf16x8*>(brow + kb + 64);
        }
        __syncthreads();
        bf16x8 af = *reinterpret_cast<const bf16x8*>(&As[(w * 16 + l16) * 40 + quad * 8]);
        #pragma unroll
        for (int nt = 0; nt < 4; ++nt) {
            bf16x8 bf = *reinterpret_cast<const bf16x8*>(&Bs[(nt * 16 + l16) * 40 + quad * 8]);
            acc[nt] = __builtin_amdgcn_mfma_f32_16x16x32_bf16(af, bf, acc[nt], 0, 0, 0);
        }
    }
    #pragma unroll
    for (int nt = 0; nt < 4; ++nt)
        #pragma unroll
        for (int i = 0; i < 4; ++i) {
            int m = m0 + w * 16 + quad * 4 + i;
            int n = n0 + nt * 16 + l16;
            if (mode == 0) {
                C[(size_t)m * ldc + n] = acc[nt][i];
            } else {
                int bidx = (((n & 63) << 6) | (n >> 6));
                float v = acc[nt][i] + bias[bidx];
                v = fmaxf(v, 0.0f);
                Cb[(size_t)m * ldc + n] = f2bf(v);
            }
        }
}

// cmat-small: cmat[e,o] = sum_p M1[e,p] * ntW[o,p]; M1 summed from 8 cpT
// partials inline (K=64, 2 MFMA steps; both stages preloaded).
static __device__ __forceinline__ void cmat_small_core(
    const float* __restrict__ Ap,
    const unsigned short* __restrict__ Wb,
    float* __restrict__ cmatT, int bm,
    unsigned short* __restrict__ As, unsigned short* __restrict__ Bs)
{
    const int t = threadIdx.x;
    const int w = t >> 6, lane = t & 63, l16 = lane & 15, quad = lane >> 4;
    const int m0 = bm * 64;
    const int r = t >> 2, koff = (t & 3) * 8;

    float a8_0[8], a8_1[8];
    #pragma unroll
    for (int half = 0; half < 2; ++half) {
        float* dst = half ? a8_1 : a8_0;
        const float* base = &Ap[(size_t)(m0 + r) * 64 + half * 32 + koff];
        float4 s0 = *reinterpret_cast<const float4*>(base);
        float4 s1 = *reinterpret_cast<const float4*>(base + 4);
        #pragma unroll
        for (int j = 1; j < 8; ++j) {
            const float* pj = base + (size_t)j * 135168L;
            float4 p0 = *reinterpret_cast<const float4*>(pj);
            float4 p1 = *reinterpret_cast<const float4*>(pj + 4);
            s0.x += p0.x; s0.y += p0.y; s0.z += p0.z; s0.w += p0.w;
            s1.x += p1.x; s1.y += p1.y; s1.z += p1.z; s1.w += p1.w;
        }
        dst[0] = s0.x; dst[1] = s0.y; dst[2] = s0.z; dst[3] = s0.w;
        dst[4] = s1.x; dst[5] = s1.y; dst[6] = s1.z; dst[7] = s1.w;
    }
    bf16x8 bv0 = *reinterpret_cast<const bf16x8*>(&Wb[(size_t)r * 64 + koff]);
    bf16x8 bv1 = *reinterpret_cast<const bf16x8*>(&Wb[(size_t)r * 64 + 32 + koff]);

    f32x4 acc[4] = {};
    #pragma unroll
    for (int kb = 0; kb < 2; ++kb) {
        const float* a8 = kb ? a8_1 : a8_0;
        __syncthreads();
        ushort4 lo, hi;
        lo.x = f2bf(a8[0]); lo.y = f2bf(a8[1]); lo.z = f2bf(a8[2]); lo.w = f2bf(a8[3]);
        hi.x = f2bf(a8[4]); hi.y = f2bf(a8[5]); hi.z = f2bf(a8[6]); hi.w = f2bf(a8[7]);
        *reinterpret_cast<ushort4*>(&As[r * 40 + koff]) = lo;
        *reinterpret_cast<ushort4*>(&As[r * 40 + koff + 4]) = hi;
        *reinterpret_cast<bf16x8*>(&Bs[r * 40 + koff]) = kb ? bv1 : bv0;
        __syncthreads();
        bf16x8 af = *reinterpret_cast<const bf16x8*>(&As[(w * 16 + l16) * 40 + quad * 8]);
        #pragma unroll
        for (int nt = 0; nt < 4; ++nt) {
            bf16x8 bf = *reinterpret_cast<const bf16x8*>(&Bs[(nt * 16 + l16) * 40 + quad * 8]);
            acc[nt] = __builtin_amdgcn_mfma_f32_16x16x32_bf16(af, bf, acc[nt], 0, 0, 0);
        }
    }
    #pragma unroll
    for (int nt = 0; nt < 4; ++nt)
        #pragma unroll
        for (int i = 0; i < 4; ++i) {
            int m = m0 + w * 16 + quad * 4 + i;   // e
            int n = nt * 16 + l16;                // o
            cmatT[(size_t)m * 64 + n] = acc[nt][i];
        }
}

static __device__ __forceinline__ void nt1f_phase(
    int b, unsigned short* __restrict__ smemu,
    const unsigned short* __restrict__ hbT, const unsigned short* __restrict__ Wb,
    unsigned short* __restrict__ nt1b)
{
    unsigned short* HtT   = smemu;             // [64][72]
    unsigned short* nt1_s = smemu + 64 * 72;   // [64][72]
    const int t = threadIdx.x;
    const int w = t >> 6, lane = t & 63, l16 = lane & 15, quad = lane >> 4;

    const unsigned short* src = hbT + (size_t)b * 4096;
    #pragma unroll
    for (int j = 0; j < 2; ++j) {
        int c = t + j * 256;
        *reinterpret_cast<bf16x8*>(&HtT[(c >> 3) * 72 + (c & 7) * 8]) =
            *reinterpret_cast<const bf16x8*>(&src[c * 8]);
    }
    __syncthreads();

    bf16x8 aW[2];
    #pragma unroll
    for (int h = 0; h < 2; ++h)
        aW[h] = *reinterpret_cast<const bf16x8*>(&Wb[(w * 16 + l16) * 64 + h * 32 + quad * 8]);
    #pragma unroll
    for (int dt = 0; dt < 4; ++dt) {
        f32x4 acc = {0.0f, 0.0f, 0.0f, 0.0f};
        #pragma unroll
        for (int h = 0; h < 2; ++h) {
            bf16x8 bf = *reinterpret_cast<const bf16x8*>(
                &HtT[(dt * 16 + l16) * 72 + h * 32 + quad * 8]);
            acc = __builtin_amdgcn_mfma_f32_16x16x32_bf16(aW[h], bf, acc, 0, 0, 0);
        }
        #pragma unroll
        for (int i = 0; i < 4; ++i)
            nt1_s[(w * 16 + quad * 4 + i) * 72 + dt * 16 + l16] = f2bf(acc[i]);
    }
    __syncthreads();
    #pragma unroll
    for (int j = 0; j < 2; ++j) {
        int c = t + j * 256;
        *reinterpret_cast<bf16x8*>(&nt1b[(size_t)b * 4096 + c * 8]) =
            *reinterpret_cast<const bf16x8*>(&nt1_s[(c >> 3) * 72 + (c & 7) * 8]);
    }
}

// ---------------------------------------------------------------------------
// Uber kernels (6-stage schedule)
// ---------------------------------------------------------------------------
__global__ __launch_bounds__(256) void uberA(   // fc_in GEMM + conv + coef
    const float* x, const float* fcinW, float* h1p,
    const float* fc1W, const float* ntW, const float* out1W, const float* tgw,
    unsigned short* fc1Wb, unsigned short* Wb, unsigned short* out1WbT,
    unsigned short* Gb,
    const float* coef_m, const float* cW, const float* cB, const float* attW,
    float* cfs)
{
    __shared__ __align__(16) float smemf[2560];
    int bx = blockIdx.x;
    if (bx < 512) {
        unsigned short* As = (unsigned short*)smemf;
        gemm_xfs_core(x, fcinW, h1p, 1024, 524288L,
                      bx & 15, (bx >> 4) & 7, bx >> 7, As, As + 2560);
    } else if (bx < 512 + CONV_BLOCKS) {
        conv_phase(bx - 512, fc1W, ntW, out1W, tgw, fc1Wb, Wb, out1WbT, Gb);
    } else {
        coef_phase(bx - (512 + CONV_BLOCKS), smemf, coef_m, cW, cB, attW, cfs);
    }
}

__global__ __launch_bounds__(256) void uberB(   // fc1 GEMM(fa, nparts=4) + att
    const float* h1p, const float* fc_in_b, const unsigned short* fc1Wb,
    float* h2p,
    const float* cfs, const float* oattW, unsigned short* attb)
{
    __shared__ __align__(16) float smemf[2560];
    int bx = blockIdx.x;
    if (bx < 64) {
        unsigned short* As = (unsigned short*)smemf;
        gemm_fa_core(h1p, 1024, 524288L, 4, fc_in_b, fc1Wb, 1024,
                     h2p, nullptr, 128, 65536L, nullptr, 0, 256,
                     bx & 1, (bx >> 1) & 7, bx >> 4, As, As + 2560);
    } else {
        int b2 = bx - 64;
        att_phase(b2 & 63, b2 >> 6, smemf, cfs, oattW, attb);
    }
}

__global__ __launch_bounds__(256) void uberC(   // M1 GEMM (ksplit 8) + out1 GEMM(fa)
    const float* tgw, const unsigned short* attb, float* cpT,
    const float* h2p, const float* fc1_b, const unsigned short* out1WbT,
    unsigned short* hbT, const float* out1_b)
{
    __shared__ __align__(16) float smemf[2560];
    unsigned short* As = (unsigned short*)smemf;
    int bx = blockIdx.x;
    if (bx < 264) {   // m in [0,33), z in [0,8)
        gemm_tgwa_core(tgw, attb, cpT, 135168L, 256,
                       bx % 33, bx / 33, As, As + 2560);
    } else {
        int b2 = bx - 264;
        gemm_fa_core(h2p, 128, 65536L, 4, fc1_b, out1WbT, 128,
                     nullptr, hbT, 4096, 0L, out1_b, 2, 128,
                     b2 & 63, b2 >> 6, 0, As, As + 2560);
    }
}

__global__ __launch_bounds__(256) void uberD(   // nt1f + cmat-small
    const unsigned short* hbT, const unsigned short* Wb, unsigned short* nt1b,
    const float* cpT, float* cmatT)
{
    __shared__ __align__(16) float smemf[4608];
    int bx = blockIdx.x;
    if (bx < 512) {
        nt1f_phase(bx, (unsigned short*)smemf, hbT, Wb, nt1b);
    } else {
        unsigned short* As = (unsigned short*)smemf;
        cmat_small_core(cpT, Wb, cmatT, bx - 512, As, As + 2560);
    }
}

// ---------------------------------------------------------------------------
// final_nb: barrier-free, LDS-free final. grid (33, 32).
// ---------------------------------------------------------------------------
__global__ __launch_bounds__(256) void final_nb(
    const unsigned short* __restrict__ nt1b, // [512][64][64] bf16
    const unsigned short* __restrict__ Gb,   // [2112,64] bf16
    const float* __restrict__ cmatT,  // [2112,64]
    const float* __restrict__ outW,   // [2112]
    float* __restrict__ zpart)        // [33][512][64]
{
    const int t = threadIdx.x;
    const int w = t >> 6, lane = t & 63, l16 = lane & 15, quad = lane >> 4;
    const int eb = blockIdx.x;
    const int b0 = blockIdx.y * 16;
    const int o = w * 16 + l16;

    bf16x8 ga[4][2];
    float cm[4][4], wv[4][4];
    #pragma unroll
    for (int et = 0; et < 4; ++et) {
        #pragma unroll
        for (int h = 0; h < 2; ++h)
            ga[et][h] = *reinterpret_cast<const bf16x8*>(
                &Gb[(size_t)(eb * 64 + et * 16 + l16) * 64 + h * 32 + quad * 8]);
        #pragma unroll
        for (int i = 0; i < 4; ++i) {
            int e = eb * 64 + et * 16 + quad * 4 + i;
            cm[et][i] = cmatT[(size_t)e * 64 + o];
            wv[et][i] = outW[e];
        }
    }

    const unsigned short* bbase = nt1b + (size_t)b0 * 4096 + o * 64 + quad * 8;
    bf16x8 bf0 = *reinterpret_cast<const bf16x8*>(bbase);
    bf16x8 bf1 = *reinterpret_cast<const bf16x8*>(bbase + 32);

    for (int bi = 0; bi < 16; ++bi) {
        bf16x8 nb0, nb1;
        if (bi < 15) {
            nb0 = *reinterpret_cast<const bf16x8*>(bbase + (size_t)(bi + 1) * 4096);
            nb1 = *reinterpret_cast<const bf16x8*>(bbase + (size_t)(bi + 1) * 4096 + 32);
        }
        float zo = 0.0f;
        #pragma unroll
        for (int et = 0; et < 4; ++et) {
            f32x4 acc = {cm[et][0], cm[et][1], cm[et][2], cm[et][3]};
            acc = __builtin_amdgcn_mfma_f32_16x16x32_bf16(ga[et][0], bf0, acc, 0, 0, 0);
            acc = __builtin_amdgcn_mfma_f32_16x16x32_bf16(ga[et][1], bf1, acc, 0, 0, 0);
            #pragma unroll
            for (int i = 0; i < 4; ++i)
                zo += __builtin_amdgcn_rcpf(1.0f + __expf(-acc[i])) * wv[et][i];
        }
        zo += __shfl_xor(zo, 16, 64);
        zo += __shfl_xor(zo, 32, 64);
        if (quad == 0)
            zpart[((size_t)eb * 512 + b0 + bi) * 64 + o] = zo;
        bf0 = nb0; bf1 = nb1;
    }
}

// out[i] = prelu( sum_z zpart[z][i] + outB )
__global__ __launch_bounds__(256) void finish_kernel(
    const float* __restrict__ zpart, const float* __restrict__ outB,
    const float* __restrict__ preluA, float* __restrict__ out)
{
    int i = blockIdx.x * 256 + threadIdx.x;  // < 32768
    float z = 0.0f;
    for (int j = 0; j < 33; ++j) z += zpart[(size_t)j * 32768 + i];
    z += outB[0];
    float pa = preluA[0];
    out[i] = (z >= 0.0f) ? z : pa * z;
}

extern "C" void kernel_launch(void* const* d_in, const int* in_sizes, int n_in,
                              void* d_out, int out_size, void* d_ws, size_t ws_size,
                              hipStream_t stream)
{
    const float* x       = (const float*)d_in[0];
    const float* fc_in_W = (const float*)d_in[1];
    const float* fc_in_b = (const float*)d_in[2];
    const float* fc1_W   = (const float*)d_in[3];
    const float* fc1_b   = (const float*)d_in[4];
    const float* out1_W  = (const float*)d_in[5];
    const float* out1_b  = (const float*)d_in[6];
    const float* cW      = (const float*)d_in[7];
    const float* cB      = (const float*)d_in[8];
    const float* cattW   = (const float*)d_in[9];
    const float* oattW   = (const float*)d_in[10];
    const float* ntW     = (const float*)d_in[11];
    const float* tgw     = (const float*)d_in[12];
    const float* outW    = (const float*)d_in[13];
    const float* outB    = (const float*)d_in[14];
    const float* preluA  = (const float*)d_in[15];
    const float* coef_m  = (const float*)d_in[16];
    float* out = (float*)d_out;
    float* ws  = (float*)d_ws;

    // workspace layout (float offsets) — no aliasing (~29.4 MB)
    unsigned short* fc1Wb   = (unsigned short*)(ws + 0);          // 65,536 f
    unsigned short* Wb      = (unsigned short*)(ws + 65536);      // 2,048 f
    unsigned short* out1WbT = (unsigned short*)(ws + 67584);      // 262,144 f
    unsigned short* Gb      = (unsigned short*)(ws + 329728);     // 67,584 f
    float*          cfs     = ws + 397312;                        // 131,072 f
    unsigned short* attb    = (unsigned short*)(ws + 528384);     // 65,536 f
    float*          h1p     = ws + 593920;                        // 4*524,288 f
    float*          h2p     = ws + 2691072;                       // 4*65,536 f
    unsigned short* hbT     = (unsigned short*)(ws + 2953216);    // 1,048,576 f
    float*          cpT     = ws + 4001792;                       // 8*135,168 f
    float*          cmatT   = ws + 5083136;                       // 135,168 f
    unsigned short* nt1b    = (unsigned short*)(ws + 5218304);    // 1,048,576 f
    float*          zpart   = ws + 6266880;                       // 1,081,344 f
    // total 7,348,224 floats

    // K1: fc_in GEMM (f32-fused, ksplit 4, 2-deep prefetch) + conv + coef
    uberA<<<512 + CONV_BLOCKS + 1024, 256, 0, stream>>>(
        x, fc_in_W, h1p,
        fc1_W, ntW, out1_W, tgw, fc1Wb, Wb, out1WbT, Gb,
        coef_m, cW, cB, cattW, cfs);
    // K2: fc1 GEMM(fa, nparts=4) + att (bf16 out)
    uberB<<<576, 256, 0, stream>>>(h1p, fc_in_b, fc1Wb, h2p, cfs, oattW, attb);
    // K3: M1 GEMM (tgwRest @ att^T, ksplit 8) + out1 GEMM(fa)
    uberC<<<776, 256, 0, stream>>>(tgw, attb, cpT,
                                   h2p, fc1_b, out1WbT, hbT, out1_b);
    // K4: nt1f + cmat-small
    uberD<<<545, 256, 0, stream>>>(hbT, Wb, nt1b, cpT, cmatT);
    // K5: barrier-free final, K6: finish
    final_nb<<<dim3(33, 32), 256, 0, stream>>>(nt1b, Gb, cmatT, outW, zpart);
    finish_kernel<<<128, 256, 0, stream>>>(zpart, outB, preluA, out);
}